// Round 11
// baseline (126.702 us; speedup 1.0000x reference)
//
#include <hip/hip_runtime.h>
#include <hip/hip_bf16.h>

// BEV pool v2, round 11:
//  prep (one fused kernel, 1M threads):
//    - feat fp32 -> bf16 rows (2.7MB table, L2-resident on every XCD)
//    - dpack[p] = {rf[p], fp32 depth[rd[p]]}  (random depth probes done once)
//    - zero the output (replaces hipMemsetAsync dispatch)
//  main: thread = (interval, split4, lane10); 8-point unroll -> 16 loads in
//        flight per thread (8 dpack + 8 bf16x8 feat gathers). LDS combine
//        over 4 splits, exclusive store per interval (no atomics).

#define C_CH   80
#define NL     10                    // lanes per feat row (8 ch each)
#define SPLITS 4
#define IPB    8
#define BLOCK  (IPB * SPLITS * NL)   // 320
#define UNROLL 8

__device__ __forceinline__ unsigned pack2_bf16(float x, float y) {
    unsigned a = __float_as_uint(x);
    unsigned b = __float_as_uint(y);
    a = (a + 0x7fffu + ((a >> 16) & 1u)) >> 16;   // RTNE
    b = (b + 0x7fffu + ((b >> 16) & 1u)) >> 16;
    return a | (b << 16);
}

__global__ void prep_fused(const float4* __restrict__ feat4,
                           const float*  __restrict__ depth,
                           const int*    __restrict__ rd,
                           const int*    __restrict__ rf,
                           uint2* __restrict__ fbf4,     // 4 bf16 per uint2
                           uint2* __restrict__ dpack,    // {rf, depth_bits}
                           float4* __restrict__ out4,
                           int NF4, int P, int OUT4) {
    int i = blockIdx.x * blockDim.x + threadIdx.x;
    if (i < NF4) {
        float4 v = feat4[i];
        fbf4[i] = make_uint2(pack2_bf16(v.x, v.y), pack2_bf16(v.z, v.w));
    }
    if (i < P) {
        float d = depth[rd[i]];
        dpack[i] = make_uint2((unsigned)rf[i], __float_as_uint(d));
    }
    if (i < OUT4) out4[i] = make_float4(0.f, 0.f, 0.f, 0.f);
}

__device__ __forceinline__ void bf8_fma(float acc[8], float d, int4 w) {
    unsigned v[4] = {(unsigned)w.x, (unsigned)w.y, (unsigned)w.z, (unsigned)w.w};
    #pragma unroll
    for (int k = 0; k < 4; ++k) {
        float lo = __uint_as_float(v[k] << 16);
        float hi = __uint_as_float(v[k] & 0xffff0000u);
        acc[2 * k]     += d * lo;
        acc[2 * k + 1] += d * hi;
    }
}

template <bool FAST>
__global__ __launch_bounds__(BLOCK) void bev_main(
    const float*  __restrict__ depth,   // fp32 fallback
    const int*    __restrict__ rd,      // fallback
    const uint2*  __restrict__ dpack,   // {rf, depth} per point
    const int4*   __restrict__ fbf,     // bf16 rows, 10 x 16B granules/row
    const float4* __restrict__ featf,   // fp32 fallback, 20 granules/row
    const int*    __restrict__ rf,      // fallback
    const int*    __restrict__ rb,      // sorted
    const int*    __restrict__ istart,
    const int*    __restrict__ ilen,
    int n_intervals,
    int n_bev,                          // 16384
    float* __restrict__ out)            // [80][n_bev]
{
    __shared__ float red[IPB][SPLITS][NL][9];   // pad 9 to spread banks

    int tid   = threadIdx.x;
    int il    = tid / (SPLITS * NL);
    int r     = tid - il * (SPLITS * NL);
    int split = r / NL;                  // 0..3
    int l10   = r - split * NL;          // 0..9
    int interval = blockIdx.x * IPB + il;
    bool valid = interval < n_intervals;

    float acc[8] = {0.f, 0.f, 0.f, 0.f, 0.f, 0.f, 0.f, 0.f};
    int bev = 0;

    if (valid) {
        int start = istart[interval];
        int len   = ilen[interval];
        bev = rb[start];

        int i = split;
        if (FAST) {
            // 8-point unroll: 8 dpack + 8 feat gathers in flight per thread.
            for (; i + (UNROLL - 1) * SPLITS < len; i += UNROLL * SPLITS) {
                uint2 w[UNROLL];
                #pragma unroll
                for (int k = 0; k < UNROLL; ++k)
                    w[k] = dpack[start + i + k * SPLITS];
                int4 f[UNROLL];
                #pragma unroll
                for (int k = 0; k < UNROLL; ++k)
                    f[k] = fbf[(long)w[k].x * NL + l10];
                #pragma unroll
                for (int k = 0; k < UNROLL; ++k)
                    bf8_fma(acc, __uint_as_float(w[k].y), f[k]);
            }
            for (; i < len; i += SPLITS) {
                uint2 w = dpack[start + i];
                int4 f = fbf[(long)w.x * NL + l10];
                bf8_fma(acc, __uint_as_float(w.y), f);
            }
        } else {
            for (; i < len; i += SPLITS) {
                int p = start + i;
                float d = depth[rd[p]];
                int q = rf[p];
                float4 a0 = featf[(long)q * 20 + l10 * 2];
                float4 a1 = featf[(long)q * 20 + l10 * 2 + 1];
                acc[0] += d * a0.x; acc[1] += d * a0.y;
                acc[2] += d * a0.z; acc[3] += d * a0.w;
                acc[4] += d * a1.x; acc[5] += d * a1.y;
                acc[6] += d * a1.z; acc[7] += d * a1.w;
            }
        }
    }

    #pragma unroll
    for (int j = 0; j < 8; ++j) red[il][split][l10][j] = acc[j];
    __syncthreads();

    if (valid && split == 0) {
        float s[8];
        #pragma unroll
        for (int j = 0; j < 8; ++j) s[j] = acc[j];
        #pragma unroll
        for (int k = 1; k < SPLITS; ++k) {
            #pragma unroll
            for (int j = 0; j < 8; ++j) s[j] += red[il][k][l10][j];
        }
        long ob = (long)(l10 * 8) * n_bev + bev;
        #pragma unroll
        for (int j = 0; j < 8; ++j) out[ob + (long)j * n_bev] = s[j];
    }
}

extern "C" void kernel_launch(void* const* d_in, const int* in_sizes, int n_in,
                              void* d_out, int out_size, void* d_ws, size_t ws_size,
                              hipStream_t stream) {
    const float* depth = (const float*)d_in[0];
    const float* featf = (const float*)d_in[1];
    const int* ranks_depth = (const int*)d_in[2];
    const int* ranks_feat  = (const int*)d_in[3];
    const int* ranks_bev   = (const int*)d_in[4];
    // d_in[5] = bev_feat_shape (static)
    const int* interval_starts  = (const int*)d_in[6];
    const int* interval_lengths = (const int*)d_in[7];

    int P    = in_sizes[2];              // 1,000,000
    int NF   = in_sizes[1];              // 1,351,680 floats (feat)
    int NF4  = NF / 4;
    int OUT4 = out_size / 4;             // 327,680
    int n_intervals = in_sizes[6];
    int n_bev = out_size / C_CH;         // 16384
    float* out = (float*)d_out;

    // ws layout: dpack (P*8B) | fbf (NF*2B)
    size_t dpack_bytes = ((size_t)P * 8 + 15) & ~(size_t)15;
    size_t fbf_bytes   = (size_t)NF * 2;
    bool fast = ws_size >= dpack_bytes + fbf_bytes;

    uint2* dpack = (uint2*)d_ws;
    uint2* fbf4  = (uint2*)((char*)d_ws + dpack_bytes);

    if (fast) {
        int n = P;
        if (NF4 > n)  n = NF4;
        if (OUT4 > n) n = OUT4;
        prep_fused<<<(n + 255) / 256, 256, 0, stream>>>(
            (const float4*)featf, depth, ranks_depth, ranks_feat,
            (uint2*)fbf4, dpack, (float4*)out, NF4, P, OUT4);
    } else {
        hipMemsetAsync(d_out, 0, (size_t)out_size * sizeof(float), stream);
    }

    int grid = (n_intervals + IPB - 1) / IPB;
    if (fast) {
        bev_main<true><<<grid, BLOCK, 0, stream>>>(
            depth, ranks_depth, dpack, (const int4*)fbf4, (const float4*)featf,
            ranks_feat, ranks_bev, interval_starts, interval_lengths,
            n_intervals, n_bev, out);
    } else {
        bev_main<false><<<grid, BLOCK, 0, stream>>>(
            depth, ranks_depth, dpack, (const int4*)fbf4, (const float4*)featf,
            ranks_feat, ranks_bev, interval_starts, interval_lengths,
            n_intervals, n_bev, out);
    }
}

// Round 12
// 118.679 us; speedup vs baseline: 1.0676x; 1.0676x over previous
//
#include <hip/hip_runtime.h>
#include <hip/hip_bf16.h>

// BEV pool v2 (reverted to round-7 best-measured configuration):
//  prep: (a) feat fp32 -> bf16 table (RTNE) in ws: row = 80ch * 2B = 160B,
//            whole table 2.7MB -> L2-resident on every XCD.
//        (b) dgath[p] = depth[rd[p]] (random depth probes done once).
//  main: thread = (interval, split, lane10). lane10 covers 8 channels via one
//        16B bf16x8 gather. Indices/dgath read once per point. LDS combine
//        across 8 splits, exclusive store per interval (no atomics).

#define C_CH   80
#define NL     10                    // lanes per point row (8 ch each)
#define SPLITS 8
#define IPB    4
#define BLOCK  (IPB * SPLITS * NL)   // 320

__global__ void prep_kernel(const float*  __restrict__ depth,
                            const int*    __restrict__ rd,
                            const float4* __restrict__ feat4,
                            float* __restrict__ dgath,
                            uint2* __restrict__ fbf,   // 4 bf16 per uint2
                            int P, int NF4) {
    int i = blockIdx.x * blockDim.x + threadIdx.x;
    if (i < NF4) {
        float4 v = feat4[i];
        float f[4] = {v.x, v.y, v.z, v.w};
        unsigned h[4];
        #pragma unroll
        for (int k = 0; k < 4; ++k) {
            unsigned u = __float_as_uint(f[k]);
            h[k] = (u + 0x7fffu + ((u >> 16) & 1u)) >> 16;   // RTNE
        }
        uint2 o;
        o.x = h[0] | (h[1] << 16);
        o.y = h[2] | (h[3] << 16);
        fbf[i] = o;
    }
    if (i < P) dgath[i] = depth[rd[i]];
}

__device__ __forceinline__ void bf8_fma(float acc[8], float d, int4 w) {
    unsigned v[4] = {(unsigned)w.x, (unsigned)w.y, (unsigned)w.z, (unsigned)w.w};
    #pragma unroll
    for (int k = 0; k < 4; ++k) {
        float lo = __uint_as_float(v[k] << 16);
        float hi = __uint_as_float(v[k] & 0xffff0000u);
        acc[2 * k]     += d * lo;
        acc[2 * k + 1] += d * hi;
    }
}

template <bool FAST>
__global__ __launch_bounds__(BLOCK) void bev_main(
    const float*  __restrict__ depth,
    const int*    __restrict__ rd,
    const float*  __restrict__ dgath,
    const int4*   __restrict__ fbf,     // bf16 rows, 10 x 16B granules/row
    const float4* __restrict__ featf,   // fp32 fallback, 20 granules/row
    const int*    __restrict__ rf,
    const int*    __restrict__ rb,      // sorted
    const int*    __restrict__ istart,
    const int*    __restrict__ ilen,
    int n_intervals,
    int n_bev,                          // 16384
    float* __restrict__ out)            // [80][n_bev]
{
    __shared__ float red[IPB][SPLITS][NL][9];  // pad 9 to spread banks

    int tid   = threadIdx.x;
    int il    = tid / (SPLITS * NL);
    int r     = tid - il * (SPLITS * NL);
    int split = r / NL;
    int l10   = r - split * NL;          // 0..9
    int interval = blockIdx.x * IPB + il;
    bool valid = interval < n_intervals;

    float acc[8] = {0.f, 0.f, 0.f, 0.f, 0.f, 0.f, 0.f, 0.f};
    int bev = 0;

    if (valid) {
        int start = istart[interval];
        int len   = ilen[interval];
        bev = rb[start];

        int i = split;
        for (; i + SPLITS < len; i += 2 * SPLITS) {
            int p0 = start + i;
            int p1 = p0 + SPLITS;
            float d0 = FAST ? dgath[p0] : depth[rd[p0]];
            float d1 = FAST ? dgath[p1] : depth[rd[p1]];
            int q0 = rf[p0], q1 = rf[p1];
            if (FAST) {
                int4 w0 = fbf[(long)q0 * NL + l10];
                int4 w1 = fbf[(long)q1 * NL + l10];
                bf8_fma(acc, d0, w0);
                bf8_fma(acc, d1, w1);
            } else {
                float4 a0 = featf[(long)q0 * 20 + l10 * 2];
                float4 a1 = featf[(long)q0 * 20 + l10 * 2 + 1];
                float4 b0 = featf[(long)q1 * 20 + l10 * 2];
                float4 b1 = featf[(long)q1 * 20 + l10 * 2 + 1];
                acc[0] += d0 * a0.x; acc[1] += d0 * a0.y;
                acc[2] += d0 * a0.z; acc[3] += d0 * a0.w;
                acc[4] += d0 * a1.x; acc[5] += d0 * a1.y;
                acc[6] += d0 * a1.z; acc[7] += d0 * a1.w;
                acc[0] += d1 * b0.x; acc[1] += d1 * b0.y;
                acc[2] += d1 * b0.z; acc[3] += d1 * b0.w;
                acc[4] += d1 * b1.x; acc[5] += d1 * b1.y;
                acc[6] += d1 * b1.z; acc[7] += d1 * b1.w;
            }
        }
        for (; i < len; i += SPLITS) {
            int p = start + i;
            float d = FAST ? dgath[p] : depth[rd[p]];
            int q = rf[p];
            if (FAST) {
                bf8_fma(acc, d, fbf[(long)q * NL + l10]);
            } else {
                float4 a0 = featf[(long)q * 20 + l10 * 2];
                float4 a1 = featf[(long)q * 20 + l10 * 2 + 1];
                acc[0] += d * a0.x; acc[1] += d * a0.y;
                acc[2] += d * a0.z; acc[3] += d * a0.w;
                acc[4] += d * a1.x; acc[5] += d * a1.y;
                acc[6] += d * a1.z; acc[7] += d * a1.w;
            }
        }
    }

    #pragma unroll
    for (int j = 0; j < 8; ++j) red[il][split][l10][j] = acc[j];
    __syncthreads();

    if (valid && split == 0) {
        float s[8];
        #pragma unroll
        for (int j = 0; j < 8; ++j) s[j] = acc[j];
        #pragma unroll
        for (int k = 1; k < SPLITS; ++k) {
            #pragma unroll
            for (int j = 0; j < 8; ++j) s[j] += red[il][k][l10][j];
        }
        long ob = (long)(l10 * 8) * n_bev + bev;
        #pragma unroll
        for (int j = 0; j < 8; ++j) out[ob + (long)j * n_bev] = s[j];
    }
}

extern "C" void kernel_launch(void* const* d_in, const int* in_sizes, int n_in,
                              void* d_out, int out_size, void* d_ws, size_t ws_size,
                              hipStream_t stream) {
    const float*  depth = (const float*)d_in[0];
    const float4* feat4 = (const float4*)d_in[1];
    const int* ranks_depth = (const int*)d_in[2];
    const int* ranks_feat  = (const int*)d_in[3];
    const int* ranks_bev   = (const int*)d_in[4];
    // d_in[5] = bev_feat_shape (static)
    const int* interval_starts  = (const int*)d_in[6];
    const int* interval_lengths = (const int*)d_in[7];

    int P   = in_sizes[2];               // 1,000,000
    int NF  = in_sizes[1];               // 1,351,680 floats
    int NF4 = NF / 4;                    // 337,920 float4s
    int n_intervals = in_sizes[6];
    int n_bev = out_size / C_CH;         // 16384
    float* out = (float*)d_out;

    size_t dg_bytes  = ((size_t)P * sizeof(float) + 15) & ~(size_t)15;
    size_t fbf_bytes = (size_t)NF * 2;
    bool fast = ws_size >= dg_bytes + fbf_bytes;

    float* dgath = (float*)d_ws;
    uint2* fbf   = (uint2*)((char*)d_ws + dg_bytes);

    // Zero output: uncovered BEV cells must read 0 (harness poisons 0xAA).
    hipMemsetAsync(d_out, 0, (size_t)out_size * sizeof(float), stream);

    if (fast) {
        int n = P > NF4 ? P : NF4;
        int gblock = 256;
        int ggrid = (n + gblock - 1) / gblock;
        prep_kernel<<<ggrid, gblock, 0, stream>>>(depth, ranks_depth, feat4,
                                                  dgath, fbf, P, NF4);
    }

    int grid = (n_intervals + IPB - 1) / IPB;
    if (fast) {
        bev_main<true><<<grid, BLOCK, 0, stream>>>(
            depth, ranks_depth, dgath, (const int4*)fbf, feat4,
            ranks_feat, ranks_bev, interval_starts, interval_lengths,
            n_intervals, n_bev, out);
    } else {
        bev_main<false><<<grid, BLOCK, 0, stream>>>(
            depth, ranks_depth, dgath, (const int4*)fbf, feat4,
            ranks_feat, ranks_bev, interval_starts, interval_lengths,
            n_intervals, n_bev, out);
    }
}